// Round 8
// baseline (2040.206 us; speedup 1.0000x reference)
//
#include <hip/hip_runtime.h>

#define TT    1024   // timesteps
#define BATCH 2048
#define NI    6      // input dim
#define NH    38     // hidden
#define NCLS  8      // classes
#define NB    8      // batches per block  -> grid 256 = exactly 1 block/CU
#define HP1   48     // h1 row: h(38) pad(2) x(6) pad(2)
#define HP2   48     // h2 row padded to SAME stride -> literal slice offsets
#define XOFF  40     // x offset inside h1 row
#define BLK   512
#define WCH   52     // LDS weight-chunk stride (208 B = 13 x 16B -> bank spread)

typedef float4 F4;

__device__ __forceinline__ float fsig(float v)  { return __fdividef(1.0f, 1.0f + __expf(-v)); }
__device__ __forceinline__ float ftanh(float v) { return 1.0f - __fdividef(2.0f, 1.0f + __expf(2.0f * v)); }

// augmented L1 weight element: cols 0..37 = Whh0, cols 40..45 = Wih0, else 0
__device__ __forceinline__ float augw(const float* Whh, const float* Wih, int row, int c) {
    if (c < NH) return Whh[row * NH + c];
    if (c >= XOFF && c < XOFF + NI) return Wih[row * NI + (c - XOFF)];
    return 0.0f;
}
__device__ __forceinline__ F4 aug4(const float* Whh, const float* Wih, int row, int c) {
    F4 v; v.x = augw(Whh, Wih, row, c + 0); v.y = augw(Whh, Wih, row, c + 1);
    v.z = augw(Whh, Wih, row, c + 2); v.w = augw(Whh, Wih, row, c + 3); return v;
}
// zero-padded L2 weight element: cols 0..37 = W, else 0
__device__ __forceinline__ F4 ldp4(const float* W, int row, int c) {
    F4 v; v.x = (c + 0 < NH) ? W[row * NH + c + 0] : 0.0f;
          v.y = (c + 1 < NH) ? W[row * NH + c + 1] : 0.0f;
          v.z = (c + 2 < NH) ? W[row * NH + c + 2] : 0.0f;
          v.w = (c + 3 < NH) ? W[row * NH + c + 3] : 0.0f; return v;
}

// ---- DPP intra-quad butterfly add (no LDS pipe; quads are lane-aligned) ----
#define QX1(v) ((v) + __int_as_float(__builtin_amdgcn_mov_dpp(__float_as_int(v), 0xB1, 0xF, 0xF, true)))
#define QX2(v) ((v) + __int_as_float(__builtin_amdgcn_mov_dpp(__float_as_int(v), 0x4E, 0xF, 0xF, true)))

#define FMA4(T, W, H) T += W.x*H.x; T += W.y*H.y; T += W.z*H.z; T += W.w*H.w;

#define ACC16 \
    float a00=0.f,a01=0.f,a02=0.f,a03=0.f, a10=0.f,a11=0.f,a12=0.f,a13=0.f; \
    float a20=0.f,a21=0.f,a22=0.f,a23=0.f, a30=0.f,a31=0.f,a32=0.f,a33=0.f;

// k-outer slice: gates 0,1 weights from REGISTERS (wa#s, wb#s); gates 2,3
// weights from LDS chunk (wb_ + 4s / +24+4s). h reads are 2-4 distinct
// addresses per wave (broadcast-cheap); weight reads are per-lane chunks
// whose 13x16B stride spreads 8 consecutive lanes over all 8 bank-quads.
#define SLICE(s, HB) { \
    const F4 hv0 = *(const F4*)((HB) + 0*HP1 + 4*(s)); \
    const F4 hv1 = *(const F4*)((HB) + 1*HP1 + 4*(s)); \
    const F4 hv2 = *(const F4*)((HB) + 2*HP1 + 4*(s)); \
    const F4 hv3 = *(const F4*)((HB) + 3*HP1 + 4*(s)); \
    const F4 wcs = *(const F4*)(wb_ + 4*(s)); \
    const F4 wds = *(const F4*)(wb_ + 24 + 4*(s)); \
    FMA4(a00, wa##s, hv0) FMA4(a01, wb##s, hv0) FMA4(a02, wcs, hv0) FMA4(a03, wds, hv0) \
    FMA4(a10, wa##s, hv1) FMA4(a11, wb##s, hv1) FMA4(a12, wcs, hv1) FMA4(a13, wds, hv1) \
    FMA4(a20, wa##s, hv2) FMA4(a21, wb##s, hv2) FMA4(a22, wcs, hv2) FMA4(a23, wds, hv2) \
    FMA4(a30, wa##s, hv3) FMA4(a31, wb##s, hv3) FMA4(a32, wcs, hv3) FMA4(a33, wds, hv3) }

#define BXOR(OP) \
    a00=OP(a00); a01=OP(a01); a02=OP(a02); a03=OP(a03); \
    a10=OP(a10); a11=OP(a11); a12=OP(a12); a13=OP(a13); \
    a20=OP(a20); a21=OP(a21); a22=OP(a22); a23=OP(a23); \
    a30=OP(a30); a31=OP(a31); a32=OP(a32); a33=OP(a33);

#define PW(P0, P1, P2, P3, CL, WP) { \
    const float ig = fsig(bs0 + P0), fg = fsig(bs1 + P1); \
    const float gg = ftanh(bs2 + P2), og = fsig(bs3 + P3); \
    const float cc = fg * CL + ig * gg; CL = cc; \
    *(WP) = og * ftanh(cc); }

// L1: 6 slices (24 cols), pair butterfly xor1, own batches 2*sub+{0,1}
#define L1BODY(HB, WR) { \
    ACC16 \
    SLICE(0, HB) SLICE(1, HB) SLICE(2, HB) SLICE(3, HB) SLICE(4, HB) SLICE(5, HB) \
    BXOR(QX1) \
    { const float p0 = sub ? a20 : a00, p1 = sub ? a21 : a01; \
      const float p2 = sub ? a22 : a02, p3 = sub ? a23 : a03; \
      PW(p0, p1, p2, p3, cl0, WR) } \
    { const float p0 = sub ? a30 : a10, p1 = sub ? a31 : a11; \
      const float p2 = sub ? a32 : a12, p3 = sub ? a33 : a13; \
      PW(p0, p1, p2, p3, cl1, (WR) + HP1) } }

// L2: 5 slices (20 cols), quad butterfly xor1+xor2, own batch sub
#define SEL4(g) ({ const float v01_ = (sub & 1) ? a1##g : a0##g; \
                   const float v23_ = (sub & 1) ? a3##g : a2##g; \
                   (sub & 2) ? v23_ : v01_; })
#define L2BODY(HB, WR) { \
    ACC16 \
    SLICE(0, HB) SLICE(1, HB) SLICE(2, HB) SLICE(3, HB) SLICE(4, HB) \
    BXOR(QX1) BXOR(QX2) \
    const float p0 = SEL4(0), p1 = SEL4(1), p2 = SEL4(2), p3 = SEL4(3); \
    PW(p0, p1, p2, p3, cl0, WR) }

// One pipeline iteration. PF load issued FIRST (issue-early / write-late).
#define ITER(L1GO, L2GO, TNX, HB, WR, PW_) { \
    const int tnx_ = (TNX); \
    const bool pfgo_ = isPF && (tnx_ < TT); \
    float pfv_ = 0.0f; \
    if (pfgo_) pfv_ = xg[(size_t)tnx_ * NI]; \
    if (isL1) { if (L1GO) L1BODY(HB, WR) } \
    else if (isL2) { if (L2GO) L2BODY(HB, WR) } \
    if (pfgo_) *(PW_) = pfv_; \
    __syncthreads(); }

// Role layout (8 waves / 512 threads), skewed pipeline, one barrier/iter:
//   tid   0..151 : L1. pair k=tid>>1: u=k%38, b0i=(k/38)*4; sub=tid&1 ->
//                  24-col slice. Gates 0,1 in regs (48 f), gates 2,3 in LDS
//                  chunk cid=2u+sub. Owns batches b0i+2sub+{0,1}.
//   tid 152..199 : x prefetch, 1 element each, into h1buf[cur] x-cols.
//   tid 200..207 : idle.
//   tid 208..511 : L2. m=tid-208: k=m>>2 (u=k%38, b0i), sub=m&3 ->
//                  side=sub>>1 (Wih1/h1 vs Whh1/h2), half=sub&1 (20-col slice).
//                  Gates 0,1 in regs (40 f), gates 2,3 in LDS chunk cid=76+u*4+sub.
//                  Owns batch b0i+sub.
// Iter i: L1 -> h1(i), L2 -> h2(i-1). Loop i=0..TT. Final h2(TT-1) in h2buf[1].
//
// R7 post-mortem: VALU-issue-saturated (94.7%) with only ~26% useful FMA; the
// gap is AGPR-spill reads of the register-overflow weight half (allocator caps
// arch VGPRs at ~88 regardless of hints, R0-R7). Fix: keep only gates 0,1 in
// regs (fits the 88-reg budget) and serve gates 2,3 from the LDS that was a
// dummy pad -> spill traffic becomes parallel-pipe ds_reads at the BW floor.

__global__ __launch_bounds__(BLK, 2) void lstm2_kernel(
    const float* __restrict__ x,
    const float* __restrict__ Wih0, const float* __restrict__ Whh0, const float* __restrict__ b0,
    const float* __restrict__ Wih1, const float* __restrict__ Whh1, const float* __restrict__ b1,
    const float* __restrict__ Wc,   const float* __restrict__ bc,
    float* __restrict__ out)
{
    __shared__ __align__(16) float h1buf[2][NB][HP1];   // 3072 B
    __shared__ __align__(16) float h2buf[2][NB][HP2];   // 3072 B
    __shared__ __align__(16) float wlds[228 * WCH];     // 47424 B: gates 2,3 chunks
    __shared__ float ldspad[8752];                      // -> total 88576 B (R6/R7 regime)

    const int tid   = threadIdx.x;
    const int bbase = blockIdx.x * NB;

    // keep the residual pad alive (runtime-false guard)
    if (bc[0] > 3.0e38f) ldspad[tid] = x[tid];

    // zero both state buffers (pads + x slots start at 0)
    for (int idx = tid; idx < 2 * NB * HP1; idx += BLK) (&h1buf[0][0][0])[idx] = 0.0f;
    for (int idx = tid; idx < 2 * NB * HP2; idx += BLK) (&h2buf[0][0][0])[idx] = 0.0f;

    const bool isL1 = (tid < 152);
    const bool isPF = (tid >= 152) && (tid < 152 + NB * NI);
    const bool isL2 = (tid >= 208);

    int sub = 0, u = 0, b0i = 0;
    if (isL1)      { const int k = tid >> 1;  sub = tid & 1; u = k % NH; b0i = (k / NH) * 4; }
    else if (isL2) { const int m = tid - 208; const int k = m >> 2;
                     sub = m & 3; u = k % NH; b0i = (k / NH) * 4; }

    // ---- stage gates 2,3 into LDS chunks (first batch-group lanes only) ----
    if (isL1 && b0i == 0) {
        float* wd_ = &wlds[(2 * u + sub) * WCH];
        const int c = 24 * sub;
        *(F4*)(wd_ + 0)  = aug4(Whh0, Wih0, u + 2*NH, c + 0);
        *(F4*)(wd_ + 4)  = aug4(Whh0, Wih0, u + 2*NH, c + 4);
        *(F4*)(wd_ + 8)  = aug4(Whh0, Wih0, u + 2*NH, c + 8);
        *(F4*)(wd_ + 12) = aug4(Whh0, Wih0, u + 2*NH, c + 12);
        *(F4*)(wd_ + 16) = aug4(Whh0, Wih0, u + 2*NH, c + 16);
        *(F4*)(wd_ + 20) = aug4(Whh0, Wih0, u + 2*NH, c + 20);
        *(F4*)(wd_ + 24) = aug4(Whh0, Wih0, u + 3*NH, c + 0);
        *(F4*)(wd_ + 28) = aug4(Whh0, Wih0, u + 3*NH, c + 4);
        *(F4*)(wd_ + 32) = aug4(Whh0, Wih0, u + 3*NH, c + 8);
        *(F4*)(wd_ + 36) = aug4(Whh0, Wih0, u + 3*NH, c + 12);
        *(F4*)(wd_ + 40) = aug4(Whh0, Wih0, u + 3*NH, c + 16);
        *(F4*)(wd_ + 44) = aug4(Whh0, Wih0, u + 3*NH, c + 20);
    } else if (isL2 && b0i == 0) {
        float* wd_ = &wlds[(76 + u * 4 + sub) * WCH];
        const float* Wm = (sub >> 1) ? Whh1 : Wih1;
        const int c = 20 * (sub & 1);
        *(F4*)(wd_ + 0)  = ldp4(Wm, u + 2*NH, c + 0);
        *(F4*)(wd_ + 4)  = ldp4(Wm, u + 2*NH, c + 4);
        *(F4*)(wd_ + 8)  = ldp4(Wm, u + 2*NH, c + 8);
        *(F4*)(wd_ + 12) = ldp4(Wm, u + 2*NH, c + 12);
        *(F4*)(wd_ + 16) = ldp4(Wm, u + 2*NH, c + 16);
        *(F4*)(wd_ + 24) = ldp4(Wm, u + 3*NH, c + 0);
        *(F4*)(wd_ + 28) = ldp4(Wm, u + 3*NH, c + 4);
        *(F4*)(wd_ + 32) = ldp4(Wm, u + 3*NH, c + 8);
        *(F4*)(wd_ + 36) = ldp4(Wm, u + 3*NH, c + 12);
        *(F4*)(wd_ + 40) = ldp4(Wm, u + 3*NH, c + 16);
    }
    __syncthreads();
    // x(0) into slot 1 x-cols (iter 0 reads prv=1)
    if (tid < NB * NI) {
        const int b = tid / NI, j = tid % NI;
        h1buf[1][b][XOFF + j] = x[(size_t)(bbase + b) * TT * NI + j];
    }

    // ---- register weights: gates 0,1 only (shared names across roles) ----
    F4 wa0,wa1,wa2,wa3,wa4,wa5, wb0,wb1,wb2,wb3,wb4,wb5;
    {
        const F4 z = {0.f,0.f,0.f,0.f};
        wa0=z;wa1=z;wa2=z;wa3=z;wa4=z;wa5=z; wb0=z;wb1=z;wb2=z;wb3=z;wb4=z;wb5=z;
    }
    float bs0=0.f, bs1=0.f, bs2=0.f, bs3=0.f;

    const float *hb0 = nullptr, *hb1 = nullptr, *xg = nullptr, *wb_ = nullptr;
    float *wr0 = nullptr, *wr1 = nullptr, *pw0 = nullptr, *pw1 = nullptr;

    if (isL1) {
        const int c = 24 * sub;
        wa0=aug4(Whh0,Wih0,u+0*NH,c);   wa1=aug4(Whh0,Wih0,u+0*NH,c+4);
        wa2=aug4(Whh0,Wih0,u+0*NH,c+8); wa3=aug4(Whh0,Wih0,u+0*NH,c+12);
        wa4=aug4(Whh0,Wih0,u+0*NH,c+16);wa5=aug4(Whh0,Wih0,u+0*NH,c+20);
        wb0=aug4(Whh0,Wih0,u+1*NH,c);   wb1=aug4(Whh0,Wih0,u+1*NH,c+4);
        wb2=aug4(Whh0,Wih0,u+1*NH,c+8); wb3=aug4(Whh0,Wih0,u+1*NH,c+12);
        wb4=aug4(Whh0,Wih0,u+1*NH,c+16);wb5=aug4(Whh0,Wih0,u+1*NH,c+20);
        bs0=b0[u]; bs1=b0[u+NH]; bs2=b0[u+2*NH]; bs3=b0[u+3*NH];
        wb_ = &wlds[(2 * u + sub) * WCH];
        hb0 = &h1buf[1][b0i][c];            // parity0 reads PRV=1
        hb1 = &h1buf[0][b0i][c];
        wr0 = &h1buf[0][b0i + 2*sub][u];    // parity0 writes CUR=0 (2 adjacent rows)
        wr1 = &h1buf[1][b0i + 2*sub][u];
    } else if (isL2) {
        const int side = sub >> 1, half = sub & 1;
        const float* Wm = side ? Whh1 : Wih1;
        const int c = 20 * half;
        wa0=ldp4(Wm,u+0*NH,c); wa1=ldp4(Wm,u+0*NH,c+4); wa2=ldp4(Wm,u+0*NH,c+8);
        wa3=ldp4(Wm,u+0*NH,c+12); wa4=ldp4(Wm,u+0*NH,c+16);
        wb0=ldp4(Wm,u+1*NH,c); wb1=ldp4(Wm,u+1*NH,c+4); wb2=ldp4(Wm,u+1*NH,c+8);
        wb3=ldp4(Wm,u+1*NH,c+12); wb4=ldp4(Wm,u+1*NH,c+16);
        bs0=b1[u]; bs1=b1[u+NH]; bs2=b1[u+2*NH]; bs3=b1[u+3*NH];
        wb_ = &wlds[(76 + u * 4 + sub) * WCH];
        hb0 = side ? &h2buf[0][b0i][c] : &h1buf[1][b0i][c];   // parity0: h2(i-2) / h1(i-1)
        hb1 = side ? &h2buf[1][b0i][c] : &h1buf[0][b0i][c];
        wr0 = &h2buf[1][b0i + sub][u];      // parity0 writes PRV=1
        wr1 = &h2buf[0][b0i + sub][u];
    } else if (isPF) {
        const int e = tid - 152, b = e / NI, j = e % NI;
        xg  = x + (size_t)(bbase + b) * TT * NI + j;
        pw0 = &h1buf[0][b][XOFF + j];       // parity0 writes CUR=0 x-cols
        pw1 = &h1buf[1][b][XOFF + j];
    }

    float cl0 = 0.0f, cl1 = 0.0f;   // cell states (L1: 2 batches; L2: cl0)

    __syncthreads();

    // iter 0: parity0 (CUR=0, PRV=1): L1 only; PF x(1) -> h1buf[0]
    ITER(true, false, 1, hb0, wr0, pw0)

    // pairs (i, i+1) for i = 1,3,...,1023  -> iterations 1..1024
    #pragma unroll 1
    for (int i = 1; i < TT; i += 2) {
        ITER(true, true, i + 1, hb1, wr1, pw1)            // parity 1
        ITER(i + 1 < TT, true, i + 2, hb0, wr0, pw0)      // parity 0
    }

    // epilogue: out = h2(TT-1) @ Wc.T + bc ; final h2 in h2buf[1]
    if (tid < NB * NCLS) {
        const int b = tid >> 3, c = tid & 7;
        float acc = bc[c];
        #pragma unroll
        for (int k = 0; k < NH; ++k) acc += Wc[c * NH + k] * h2buf[1][b][k];
        out[(size_t)(bbase + b) * NCLS + c] = acc;
    }
    if (bc[0] > 3.0e38f) out[tid] = ldspad[BLK - tid];
}

extern "C" void kernel_launch(void* const* d_in, const int* in_sizes, int n_in,
                              void* d_out, int out_size, void* d_ws, size_t ws_size,
                              hipStream_t stream) {
    const float* x    = (const float*)d_in[0];
    const float* Wih0 = (const float*)d_in[1];
    const float* Whh0 = (const float*)d_in[2];
    const float* b0   = (const float*)d_in[3];
    const float* Wih1 = (const float*)d_in[4];
    const float* Whh1 = (const float*)d_in[5];
    const float* b1   = (const float*)d_in[6];
    const float* Wc   = (const float*)d_in[7];
    const float* bc   = (const float*)d_in[8];
    float* out = (float*)d_out;

    dim3 grid(BATCH / NB);
    dim3 block(BLK);
    hipLaunchKernelGGL(lstm2_kernel, grid, block, 0, stream,
                       x, Wih0, Whh0, b0, Wih1, Whh1, b1, Wc, bc, out);
}

// Round 9
// 1276.517 us; speedup vs baseline: 1.5983x; 1.5983x over previous
//
#include <hip/hip_runtime.h>

#define TT    1024   // timesteps
#define BATCH 2048
#define NI    6      // input dim
#define NH    38     // hidden
#define NG    152    // 4*NH
#define NCLS  8      // classes
#define NB    8      // batches per block -> grid 256 = 1 block/CU
#define BLK   640    // 10 waves: 5 L1 + 5 L2, 2 M-tiles each
#define KP1   68     // L1 B-row stride (f16): 64 K-slots + pad (136B, 8B-aligned)
#define KP2   100    // L2 B-row stride: 96 K-slots + pad (200B, 2-way-free banks)
#define XK    40     // x k-offset inside L1 K-space (h1: 0..37)
#define H2K   48     // h2 k-offset inside L2 K-space (h1: 0..37)

typedef _Float16 f16;
typedef _Float16 f16x4 __attribute__((ext_vector_type(4)));
typedef _Float16 f16x8 __attribute__((ext_vector_type(8)));
typedef float    f32x4 __attribute__((ext_vector_type(4)));

__device__ __forceinline__ float fsig(float v)  { return __fdividef(1.0f, 1.0f + __expf(-v)); }
__device__ __forceinline__ float ftanh(float v) { return 1.0f - __fdividef(2.0f, 1.0f + __expf(2.0f*v)); }

// ---- weight element in gate-interleaved augmented K-space ----
// row r = 4*u + g  (u: unit, g: gate i/f/g/o)  -> unit's 4 gates land in one
// lane's 4 C-regs (C/D layout: col=lane&15, row=(lane>>4)*4+reg, m89-verified).
__device__ __forceinline__ float wget1(const float* Wih0, const float* Whh0, int r, int k) {
    if (r >= NG) return 0.0f;
    const int u = r >> 2, g = r & 3;
    if (k < NH) return Whh0[(size_t)(g*NH + u)*NH + k];
    if (k >= XK && k < XK + NI) return Wih0[(size_t)(g*NH + u)*NI + (k - XK)];
    return 0.0f;
}
__device__ __forceinline__ float wget2(const float* Wih1, const float* Whh1, int r, int k) {
    if (r >= NG) return 0.0f;
    const int u = r >> 2, g = r & 3;
    if (k < NH) return Wih1[(size_t)(g*NH + u)*NH + k];
    if (k >= H2K && k < H2K + NH) return Whh1[(size_t)(g*NH + u)*NH + (k - H2K)];
    return 0.0f;
}

// k-slot convention (same for A and B => any layout-guess error cancels inside
// the MFMA dot): elem e of lane l covers k = 32F + (e<4 ? qq*4+e : 16+qq*4+e-4),
// qq = l>>4. A fragment: m = l&15. B fragment: n = l&15.
__device__ __forceinline__ f16x8 ldA1(const float* Wih0, const float* Whh0,
                                      int Tg, int F, int m16, int qq) {
    f16x8 r;
    #pragma unroll
    for (int e = 0; e < 8; ++e) {
        const int kk = 32*F + ((e < 4) ? (qq*4 + e) : (16 + qq*4 + e - 4));
        r[e] = (f16)wget1(Wih0, Whh0, 16*Tg + m16, kk);
    }
    return r;
}
__device__ __forceinline__ f16x8 ldA2(const float* Wih1, const float* Whh1,
                                      int Tg, int F, int m16, int qq) {
    f16x8 r;
    #pragma unroll
    for (int e = 0; e < 8; ++e) {
        const int kk = 32*F + ((e < 4) ? (qq*4 + e) : (16 + qq*4 + e - 4));
        r[e] = (f16)wget2(Wih1, Whh1, 16*Tg + m16, kk);
    }
    return r;
}

// B fragment: batch-major LDS rows make lane elems contiguous: 2x f16x4 reads.
__device__ __forceinline__ f16x8 ldB(const f16* rb, int off) {
    const f16x4 lo = *(const f16x4*)(rb + off);
    const f16x4 hi = *(const f16x4*)(rb + off + 16);
    f16x8 r;
    r[0]=lo[0]; r[1]=lo[1]; r[2]=lo[2]; r[3]=lo[3];
    r[4]=hi[0]; r[5]=hi[1]; r[6]=hi[2]; r[7]=hi[3];
    return r;
}

#define MFMA16(A, B, C) __builtin_amdgcn_mfma_f32_16x16x32_f16(A, B, C, 0, 0, 0)

// pointwise: lane's 4 C-regs are (i,f,g,o) of one (unit,batch); c-state f32.
#define PWCORE(A, CREG) \
    const float ig = fsig((A)[0] + bsv0), fg = fsig((A)[1] + bsv1); \
    const float gg = ftanh((A)[2] + bsv2), og = fsig((A)[3] + bsv3); \
    const float cc = fg * (CREG) + ig * gg; (CREG) = cc; \
    const f16 hv = (f16)(og * ftanh(cc));

// Skewed pipeline (R2-verified): iter i computes h1(i) [L1 waves] and h2(i-1)
// [L2 waves]; reads slot s^1, writes slot s=i&1 -> ONE barrier per iteration.
// Final h2(TT-1) written at iter TT into slot 0.

__global__ __launch_bounds__(BLK, 1) void lstm2_kernel(
    const float* __restrict__ x,
    const float* __restrict__ Wih0, const float* __restrict__ Whh0, const float* __restrict__ b0,
    const float* __restrict__ Wih1, const float* __restrict__ Whh1, const float* __restrict__ b1,
    const float* __restrict__ Wc,   const float* __restrict__ bc,
    float* __restrict__ out)
{
    __shared__ __align__(16) f16 l1buf[2][16][KP1];   // 4352 B  [slot][batch][K]
    __shared__ __align__(16) f16 l2buf[2][16][KP2];   // 6400 B
    __shared__ float ldspad[19456];                   // -> total 88576 B (1 block/CU regime)

    const int tid   = threadIdx.x;
    const int bbase = blockIdx.x * NB;
    const int wid   = tid >> 6, lane = tid & 63;
    const int n     = lane & 15, qq = lane >> 4;

    if (bc[0] > 3.0e38f) ldspad[tid] = x[tid];   // keep pad alive (runtime-false)

    // zero both slots of both B-buffers (pads + pad-batches stay 0 forever)
    {
        int* p1 = (int*)&l1buf[0][0][0];
        for (int idx = tid; idx < 2*16*KP1/2; idx += BLK) p1[idx] = 0;
        int* p2 = (int*)&l2buf[0][0][0];
        for (int idx = tid; idx < 2*16*KP2/2; idx += BLK) p2[idx] = 0;
    }
    __syncthreads();
    // x(0) into slot 1 (iter 0 reads rs=1)
    if (tid < NB * NI) {
        const int b = tid / NI, j = tid % NI;
        l1buf[1][b][XK + j] = (f16)x[(size_t)(bbase + b)*TT*NI + j];
    }

    const bool isL1 = (wid < 5);
    const int  T0   = 2 * (isL1 ? wid : wid - 5);   // first of 2 M-tiles
    const int  u0   = 4*T0 + qq, u1 = u0 + 4;       // this lane's units
    const bool wen0 = (u0 < NH) && (n < NB);
    const bool wen1 = (u1 < NH) && (n < NB);

    // ---- persistent A-fragments (weights): 2 tiles x <=3 K-frags = <=24 VGPR ----
    f16x8 w00, w01, w02, w10, w11, w12;
    float bs00=0.f,bs01=0.f,bs02=0.f,bs03=0.f, bs10=0.f,bs11=0.f,bs12=0.f,bs13=0.f;
    {
        f16x8 z8; 
        #pragma unroll
        for (int e = 0; e < 8; ++e) z8[e] = (f16)0;
        w02 = z8; w12 = z8;
        if (isL1) {
            w00 = ldA1(Wih0, Whh0, T0,   0, n, qq);
            w01 = ldA1(Wih0, Whh0, T0,   1, n, qq);
            w10 = ldA1(Wih0, Whh0, T0+1, 0, n, qq);
            w11 = ldA1(Wih0, Whh0, T0+1, 1, n, qq);
            if (u0 < NH) { bs00=b0[u0]; bs01=b0[NH+u0]; bs02=b0[2*NH+u0]; bs03=b0[3*NH+u0]; }
            if (u1 < NH) { bs10=b0[u1]; bs11=b0[NH+u1]; bs12=b0[2*NH+u1]; bs13=b0[3*NH+u1]; }
        } else {
            w00 = ldA2(Wih1, Whh1, T0,   0, n, qq);
            w01 = ldA2(Wih1, Whh1, T0,   1, n, qq);
            w02 = ldA2(Wih1, Whh1, T0,   2, n, qq);
            w10 = ldA2(Wih1, Whh1, T0+1, 0, n, qq);
            w11 = ldA2(Wih1, Whh1, T0+1, 1, n, qq);
            w12 = ldA2(Wih1, Whh1, T0+1, 2, n, qq);
            if (u0 < NH) { bs00=b1[u0]; bs01=b1[NH+u0]; bs02=b1[2*NH+u0]; bs03=b1[3*NH+u0]; }
            if (u1 < NH) { bs10=b1[u1]; bs11=b1[NH+u1]; bs12=b1[2*NH+u1]; bs13=b1[3*NH+u1]; }
        }
    }

    // x prefetch role: wave 0 lanes 0..47 (also L1 lanes; issue-early/write-late)
    const bool isPF = (tid < NB * NI);
    const float* xptr = nullptr;
    f16 *pfw0 = nullptr, *pfw1 = nullptr;
    if (isPF) {
        const int b = tid / NI, j = tid % NI;
        xptr = x + (size_t)(bbase + b)*TT*NI + NI + j;    // points at x(1) elem
        pfw0 = &l1buf[0][b][XK + j];
        pfw1 = &l1buf[1][b][XK + j];
    }

    float c0 = 0.0f, c1 = 0.0f;   // f32 cell states for this lane's 2 (unit,batch)

    __syncthreads();

    #pragma unroll 1
    for (int i = 0; i <= TT; ++i) {
        const int s = i & 1, rs = s ^ 1;

        float xv = 0.0f;
        const bool pf = isPF && (i + 1 < TT);
        if (pf) xv = *xptr;                       // issue early

        if (isL1) {
            if (i < TT) {
                const f16* rb = &l1buf[rs][n][0];
                const f16x8 B0 = ldB(rb, 4*qq);
                const f16x8 B1 = ldB(rb, 32 + 4*qq);
                f32x4 a0 = {0.f,0.f,0.f,0.f}, a1 = {0.f,0.f,0.f,0.f};
                a0 = MFMA16(w00, B0, a0);
                a0 = MFMA16(w01, B1, a0);
                a1 = MFMA16(w10, B0, a1);
                a1 = MFMA16(w11, B1, a1);
                {
                    const float bsv0=bs00, bsv1=bs01, bsv2=bs02, bsv3=bs03;
                    PWCORE(a0, c0)
                    if (wen0) { l1buf[s][n][u0] = hv; l2buf[s][n][u0] = hv; }
                }
                {
                    const float bsv0=bs10, bsv1=bs11, bsv2=bs12, bsv3=bs13;
                    PWCORE(a1, c1)
                    if (wen1) { l1buf[s][n][u1] = hv; l2buf[s][n][u1] = hv; }
                }
            }
        } else {
            if (i >= 1) {
                const f16* rb = &l2buf[rs][n][0];
                const f16x8 B0 = ldB(rb, 4*qq);
                const f16x8 B1 = ldB(rb, 32 + 4*qq);
                const f16x8 B2 = ldB(rb, 64 + 4*qq);
                f32x4 a0 = {0.f,0.f,0.f,0.f}, a1 = {0.f,0.f,0.f,0.f};
                a0 = MFMA16(w00, B0, a0);
                a0 = MFMA16(w01, B1, a0);
                a0 = MFMA16(w02, B2, a0);
                a1 = MFMA16(w10, B0, a1);
                a1 = MFMA16(w11, B1, a1);
                a1 = MFMA16(w12, B2, a1);
                {
                    const float bsv0=bs00, bsv1=bs01, bsv2=bs02, bsv3=bs03;
                    PWCORE(a0, c0)
                    if (wen0) l2buf[s][n][H2K + u0] = hv;
                }
                {
                    const float bsv0=bs10, bsv1=bs11, bsv2=bs12, bsv3=bs13;
                    PWCORE(a1, c1)
                    if (wen1) l2buf[s][n][H2K + u1] = hv;
                }
            }
        }

        if (pf) { *(s ? pfw1 : pfw0) = (f16)xv; xptr += NI; }   // write late
        __syncthreads();
    }

    // epilogue: out = h2(TT-1) @ Wc.T + bc ; final h2 in l2buf[0][b][H2K+.]
    if (tid < NB * NCLS) {
        const int b = tid >> 3, c = tid & 7;
        float a = bc[c];
        #pragma unroll
        for (int k = 0; k < NH; ++k)
            a += Wc[c*NH + k] * (float)l2buf[0][b][H2K + k];
        out[(size_t)(bbase + b)*NCLS + c] = a;
    }
    if (bc[0] > 3.0e38f) out[tid] = ldspad[BLK - tid];
}

extern "C" void kernel_launch(void* const* d_in, const int* in_sizes, int n_in,
                              void* d_out, int out_size, void* d_ws, size_t ws_size,
                              hipStream_t stream) {
    const float* x    = (const float*)d_in[0];
    const float* Wih0 = (const float*)d_in[1];
    const float* Whh0 = (const float*)d_in[2];
    const float* b0   = (const float*)d_in[3];
    const float* Wih1 = (const float*)d_in[4];
    const float* Whh1 = (const float*)d_in[5];
    const float* b1   = (const float*)d_in[6];
    const float* Wc   = (const float*)d_in[7];
    const float* bc   = (const float*)d_in[8];
    float* out = (float*)d_out;

    dim3 grid(BATCH / NB);
    dim3 block(BLK);
    hipLaunchKernelGGL(lstm2_kernel, grid, block, 0, stream,
                       x, Wih0, Whh0, b0, Wih1, Whh1, b1, Wc, bc, out);
}